// Round 1
// baseline (1891.464 us; speedup 1.0000x reference)
//
#include <hip/hip_runtime.h>
#include <hip/hip_fp16.h>

#define NTOK   49
#define DIMM   384
#define NHEAD  12
#define HD     32
#define BNWIN  4096        // 64 windows * 64 batch
#define MROWS  200704      // BNWIN * NTOK

typedef _Float16 half8 __attribute__((ext_vector_type(8)));
typedef float    f32x4 __attribute__((ext_vector_type(4)));

// workspace layout (byte offsets, 256-aligned)
#define WQH_OFF   0u           // 442368 halves  (884736 B)
#define WPH_OFF   884736u      // 147456 halves  (294912 B)
#define RB_OFF    1179648u     // 28812 floats   (115248 B)   legacy rb
#define RBM_OFF   1295104u     // 1843968 floats (7375872 B)  rb+mask combined
#define CTX_OFF   8670976u     // 77070336 halves (154140672 B)
#define XH_OFF    162811648u   // 77070336 halves (154140672 B)
#define CTXL_OFF  1295104u     // legacy ctx offset (no rbm/xh)
#define WS_NEED_XH   316952320u
#define WS_NEED_RBM  162811648u

// ---------------------------------------------------------------------------
// Kernel 0: weight conversion + rel-pos-bias gather (+ combined bias+mask tbl)
// ---------------------------------------------------------------------------
__global__ __launch_bounds__(256) void prep_kernel(
    const float* __restrict__ wqkv, const float* __restrict__ wproj,
    const float* __restrict__ btab, const float* __restrict__ mask,
    _Float16* __restrict__ wq_h, _Float16* __restrict__ wp_h,
    float* __restrict__ rb, float* __restrict__ rbm, int do_rbm)
{
    int idx = blockIdx.x * 256 + threadIdx.x;
    if (idx < 442368) wq_h[idx] = (_Float16)wqkv[idx];
    if (idx < 147456) wp_h[idx] = (_Float16)wproj[idx];
    if (idx < 28812) {
        int h  = idx / 2401;
        int ij = idx - h * 2401;
        int i  = ij / 49;
        int j  = ij - i * 49;
        int ih = i / 7, iw = i - ih * 7;
        int jh = j / 7, jw = j - jh * 7;
        int rel = (ih - jh + 6) * 13 + (iw - jw + 6);
        rb[idx] = btab[rel * 12 + h];
    }
    if (do_rbm && idx < 1843968) {
        // rbm[wm][h][i][j] = rb[h][i][j] + mask[wm][i][j]
        int wm  = idx / 28812;
        int rem = idx - wm * 28812;
        int h   = rem / 2401;
        int ij  = rem - h * 2401;
        int i   = ij / 49;
        int j   = ij - i * 49;
        int ih = i / 7, iw = i - ih * 7;
        int jh = j / 7, jw = j - jh * 7;
        int rel = (ih - jh + 6) * 13 + (iw - jw + 6);
        rbm[idx] = btab[rel * 12 + h] + mask[wm * 2401 + ij];
    }
}

// ---------------------------------------------------------------------------
// Kernel 0b: x fp32 -> fp16 (one-shot, BW-bound)
// ---------------------------------------------------------------------------
__global__ __launch_bounds__(256) void xcvt_kernel(
    const float* __restrict__ x, _Float16* __restrict__ xh)
{
    const size_t total = (size_t)MROWS * DIMM;   // 77070336, divisible by 8
    size_t i = ((size_t)blockIdx.x * 256 + threadIdx.x) * 8;
    const size_t step = (size_t)gridDim.x * 256 * 8;
    for (; i < total; i += step) {
        float4 a0 = *(const float4*)(x + i);
        float4 a1 = *(const float4*)(x + i + 4);
        half8 t;
        t[0] = (_Float16)a0.x; t[1] = (_Float16)a0.y;
        t[2] = (_Float16)a0.z; t[3] = (_Float16)a0.w;
        t[4] = (_Float16)a1.x; t[5] = (_Float16)a1.y;
        t[6] = (_Float16)a1.z; t[7] = (_Float16)a1.w;
        *(half8*)(xh + i) = t;
    }
}

// ---------------------------------------------------------------------------
// Kernel 1: fused QKV projection + windowed attention (one block per window)
// 256 threads = 4 waves; wave w owns heads {w, w+4, w+8}; no barriers.
// V-pass (acc 32 VGPR) then QK-pass (acc 64 VGPR) to fit 3 waves/SIMD.
// ---------------------------------------------------------------------------
template<bool XHM, bool RBM>
__global__ __launch_bounds__(256, 3) void attn_kernel(
    const float* __restrict__ x, const _Float16* __restrict__ xh,
    const float* __restrict__ mask,
    const _Float16* __restrict__ wq, const float* __restrict__ bq,
    const float* __restrict__ rb, const float* __restrict__ rbm,
    _Float16* __restrict__ ctx)
{
    // per-wave LDS (halves): [0,1960) q (49x40), [1960,3920) k (49x40)
    //                        [0,3528)  p (49x72)  -- aliases q/k after use
    //                        [3920,6224) vT (32 rows d x 72 cols j)
    __shared__ _Float16 smem[4][6224];
    const int tid  = threadIdx.x;
    const int wv   = tid >> 6;
    const int lane = tid & 63;
    const int quad = lane >> 4;
    const int l16  = lane & 15;
    const int bn   = blockIdx.x;
    const int wm   = bn >> 6;          // window index (B=64)

    _Float16* q_s  = &smem[wv][0];
    _Float16* k_s  = &smem[wv][1960];
    _Float16* p_s  = &smem[wv][0];
    _Float16* vT_s = &smem[wv][3920];

    const float scale = 0.17677669529663687f;  // 32^-0.5

    int rowm[4];
#pragma unroll
    for (int mi = 0; mi < 4; ++mi) {
        int r = mi * 16 + l16;
        rowm[mi] = r > 48 ? 48 : r;    // clamp: rows >=49 are finite clones of row 48
    }

    // A-fragment loader: 4 row-tiles of x for K-chunk k
    auto load_af = [&](int k, half8* af) {
#pragma unroll
        for (int mi = 0; mi < 4; ++mi) {
            if constexpr (XHM) {
                af[mi] = *(const half8*)(xh + ((size_t)bn * NTOK + rowm[mi]) * DIMM + k * 32 + quad * 8);
            } else {
                const float* ap = x + ((size_t)bn * NTOK + rowm[mi]) * DIMM + k * 32 + quad * 8;
                float4 a0 = *(const float4*)ap;
                float4 a1 = *(const float4*)(ap + 4);
                half8 t;
                t[0] = (_Float16)a0.x; t[1] = (_Float16)a0.y;
                t[2] = (_Float16)a0.z; t[3] = (_Float16)a0.w;
                t[4] = (_Float16)a1.x; t[5] = (_Float16)a1.y;
                t[6] = (_Float16)a1.z; t[7] = (_Float16)a1.w;
                af[mi] = t;
            }
        }
    };

    for (int hh = 0; hh < 3; ++hh) {
        const int h = wv + (hh << 2);

        // ---- V pass: v = x @ Wv^T (32 cols), K=384; scatter transposed ----
        {
            f32x4 av[2][4];
#pragma unroll
            for (int nv = 0; nv < 2; ++nv)
#pragma unroll
                for (int mi = 0; mi < 4; ++mi)
                    av[nv][mi] = (f32x4){0.f, 0.f, 0.f, 0.f};

#pragma unroll 2
            for (int k = 0; k < 12; ++k) {
                half8 af[4];
                load_af(k, af);
#pragma unroll
                for (int nv = 0; nv < 2; ++nv) {
                    const int n0 = 2 * DIMM + h * HD + nv * 16;
                    half8 bf = *(const half8*)(wq + (size_t)(n0 + l16) * DIMM + k * 32 + quad * 8);
#pragma unroll
                    for (int mi = 0; mi < 4; ++mi)
                        av[nv][mi] = __builtin_amdgcn_mfma_f32_16x16x32_f16(af[mi], bf, av[nv][mi], 0, 0, 0);
                }
            }
#pragma unroll
            for (int nv = 0; nv < 2; ++nv) {
                const int n0 = 2 * DIMM + h * HD + nv * 16;
                const float bias = bq[n0 + l16];
                const int colh = nv * 16 + l16;
#pragma unroll
                for (int mi = 0; mi < 4; ++mi)
#pragma unroll
                    for (int r = 0; r < 4; ++r) {
                        const int row = mi * 16 + quad * 4 + r;
                        vT_s[colh * 72 + row] = (_Float16)(av[nv][mi][r] + bias);  // rows>=49: finite clones, P=0 there
                    }
            }
        }

        // ---- QK pass: q,k = x @ W^T (2x32 cols); q pre-scaled ----
        {
            f32x4 aqk[4][4];
#pragma unroll
            for (int nn = 0; nn < 4; ++nn)
#pragma unroll
                for (int mi = 0; mi < 4; ++mi)
                    aqk[nn][mi] = (f32x4){0.f, 0.f, 0.f, 0.f};

#pragma unroll 2
            for (int k = 0; k < 12; ++k) {
                half8 af[4];
                load_af(k, af);
#pragma unroll
                for (int nn = 0; nn < 4; ++nn) {
                    const int n0 = (nn >> 1) * DIMM + h * HD + (nn & 1) * 16;
                    half8 bf = *(const half8*)(wq + (size_t)(n0 + l16) * DIMM + k * 32 + quad * 8);
#pragma unroll
                    for (int mi = 0; mi < 4; ++mi)
                        aqk[nn][mi] = __builtin_amdgcn_mfma_f32_16x16x32_f16(af[mi], bf, aqk[nn][mi], 0, 0, 0);
                }
            }
#pragma unroll
            for (int nn = 0; nn < 4; ++nn) {
                const int n0 = (nn >> 1) * DIMM + h * HD + (nn & 1) * 16;
                const float bias = bq[n0 + l16];
                const int colh = (nn & 1) * 16 + l16;
                if (nn < 2) {
                    const float bs = bias * scale;
#pragma unroll
                    for (int mi = 0; mi < 4; ++mi)
#pragma unroll
                        for (int r = 0; r < 4; ++r) {
                            const int row = mi * 16 + quad * 4 + r;
                            if (row < 49) q_s[row * 40 + colh] = (_Float16)(aqk[nn][mi][r] * scale + bs);
                        }
                } else {
#pragma unroll
                    for (int mi = 0; mi < 4; ++mi)
#pragma unroll
                        for (int r = 0; r < 4; ++r) {
                            const int row = mi * 16 + quad * 4 + r;
                            if (row < 49) k_s[row * 40 + colh] = (_Float16)(aqk[nn][mi][r] + bias);
                        }
                }
            }
        }

        // ---- phase 2: S = q @ k^T (q pre-scaled), K=32 single MFMA step ----
        f32x4 s[4][4];
        {
            half8 bk[4];
#pragma unroll
            for (int nj = 0; nj < 4; ++nj)
                bk[nj] = *(const half8*)(k_s + rowm[nj] * 40 + quad * 8);
#pragma unroll
            for (int mi = 0; mi < 4; ++mi) {
                half8 aq = *(const half8*)(q_s + rowm[mi] * 40 + quad * 8);
#pragma unroll
                for (int nj = 0; nj < 4; ++nj)
                    s[mi][nj] = __builtin_amdgcn_mfma_f32_16x16x32_f16(
                        aq, bk[nj], (f32x4){0.f, 0.f, 0.f, 0.f}, 0, 0, 0);
            }
        }

        // ---- phase 3: +(bias+mask), register softmax, P -> LDS ----
        const float* rbmh = RBM ? (rbm + (size_t)(wm * 12 + h) * 2401) : nullptr;
        const float* rbh  = RBM ? nullptr : (rb + h * 2401);
        const float* mkw  = RBM ? nullptr : (mask + wm * 2401);
#pragma unroll
        for (int mi = 0; mi < 4; ++mi) {
#pragma unroll
            for (int r = 0; r < 4; ++r) {
                const int i  = mi * 16 + quad * 4 + r;
                const int iq = i > 48 ? 48 : i;
                float vals[4];
                float mx = -3.0e38f;
#pragma unroll
                for (int nj = 0; nj < 4; ++nj) {
                    const int j = nj * 16 + l16;
                    float v = -1.0e30f;
                    if (j < 49) {
                        if constexpr (RBM)
                            v = s[mi][nj][r] + rbmh[iq * 49 + j];
                        else
                            v = s[mi][nj][r] + rbh[iq * 49 + j] + mkw[iq * 49 + j];
                    }
                    vals[nj] = v;
                    mx = fmaxf(mx, v);
                }
#pragma unroll
                for (int off = 8; off >= 1; off >>= 1)
                    mx = fmaxf(mx, __shfl_xor(mx, off));
                float sum = 0.f;
#pragma unroll
                for (int nj = 0; nj < 4; ++nj) {
                    vals[nj] = __expf(vals[nj] - mx);
                    sum += vals[nj];
                }
#pragma unroll
                for (int off = 8; off >= 1; off >>= 1)
                    sum += __shfl_xor(sum, off);
                const float inv = __builtin_amdgcn_rcpf(sum);
                if (i < 49) {
#pragma unroll
                    for (int nj = 0; nj < 4; ++nj)
                        p_s[i * 72 + nj * 16 + l16] = (_Float16)(vals[nj] * inv);
                }
            }
        }

        // ---- phase 4: O = P @ V ----
        f32x4 o[4][2];
#pragma unroll
        for (int mi = 0; mi < 4; ++mi)
#pragma unroll
            for (int nd = 0; nd < 2; ++nd)
                o[mi][nd] = (f32x4){0.f, 0.f, 0.f, 0.f};
#pragma unroll
        for (int ks = 0; ks < 2; ++ks) {
            half8 bv[2];
#pragma unroll
            for (int nd = 0; nd < 2; ++nd)
                bv[nd] = *(const half8*)(vT_s + (nd * 16 + l16) * 72 + ks * 32 + quad * 8);
#pragma unroll
            for (int mi = 0; mi < 4; ++mi) {
                half8 apf = *(const half8*)(p_s + rowm[mi] * 72 + ks * 32 + quad * 8);
#pragma unroll
                for (int nd = 0; nd < 2; ++nd)
                    o[mi][nd] = __builtin_amdgcn_mfma_f32_16x16x32_f16(apf, bv[nd], o[mi][nd], 0, 0, 0);
            }
        }

        // ---- phase 5: ctx out (fp16, [bn*49+i][h*32+d]) ----
#pragma unroll
        for (int mi = 0; mi < 4; ++mi) {
#pragma unroll
            for (int r = 0; r < 4; ++r) {
                const int i = mi * 16 + quad * 4 + r;
                if (i < 49) {
#pragma unroll
                    for (int nd = 0; nd < 2; ++nd) {
                        const int col = h * HD + nd * 16 + l16;
                        ctx[((size_t)bn * NTOK + i) * DIMM + col] = (_Float16)o[mi][nd][r];
                    }
                }
            }
        }
    }
}

// ---------------------------------------------------------------------------
// Kernel 2: out = ctx @ w_proj^T + b_proj   [200704,384]x[384,384]
// block = 64 rows x 384 cols; 4 waves, wave w covers cols [w*96, w*96+96)
// split into 2 passes of 3 col-tiles to cut acc VGPRs (96 -> 48)
// ---------------------------------------------------------------------------
__global__ __launch_bounds__(256, 4) void proj_kernel(
    const _Float16* __restrict__ ctx, const _Float16* __restrict__ wp,
    const float* __restrict__ bp, float* __restrict__ out)
{
    const int tid  = threadIdx.x;
    const int wv   = tid >> 6;
    const int lane = tid & 63;
    const int quad = lane >> 4;
    const int l16  = lane & 15;
    const size_t m0 = (size_t)blockIdx.x * 64;

#pragma unroll 1
    for (int pass = 0; pass < 2; ++pass) {
        f32x4 c[4][3];
#pragma unroll
        for (int mi = 0; mi < 4; ++mi)
#pragma unroll
            for (int nj = 0; nj < 3; ++nj)
                c[mi][nj] = (f32x4){0.f, 0.f, 0.f, 0.f};

#pragma unroll 2
        for (int k = 0; k < 12; ++k) {
            half8 a[4];
#pragma unroll
            for (int mi = 0; mi < 4; ++mi)
                a[mi] = *(const half8*)(ctx + (m0 + mi * 16 + l16) * DIMM + k * 32 + quad * 8);
#pragma unroll
            for (int nj = 0; nj < 3; ++nj) {
                const int n = wv * 96 + (pass * 3 + nj) * 16 + l16;
                half8 b = *(const half8*)(wp + (size_t)n * DIMM + k * 32 + quad * 8);
#pragma unroll
                for (int mi = 0; mi < 4; ++mi)
                    c[mi][nj] = __builtin_amdgcn_mfma_f32_16x16x32_f16(a[mi], b, c[mi][nj], 0, 0, 0);
            }
        }
#pragma unroll
        for (int nj = 0; nj < 3; ++nj) {
            const int n = wv * 96 + (pass * 3 + nj) * 16 + l16;
            const float bias = bp[n];
#pragma unroll
            for (int mi = 0; mi < 4; ++mi) {
#pragma unroll
                for (int r = 0; r < 4; ++r) {
                    const size_t row = m0 + mi * 16 + quad * 4 + r;
                    out[row * DIMM + n] = c[mi][nj][r] + bias;
                }
            }
        }
    }
}

// ---------------------------------------------------------------------------
extern "C" void kernel_launch(void* const* d_in, const int* in_sizes, int n_in,
                              void* d_out, int out_size, void* d_ws, size_t ws_size,
                              hipStream_t stream)
{
    const float* x     = (const float*)d_in[0];
    const float* mask  = (const float*)d_in[1];
    const float* wqkv  = (const float*)d_in[2];
    const float* bqkv  = (const float*)d_in[3];
    const float* wproj = (const float*)d_in[4];
    const float* bproj = (const float*)d_in[5];
    const float* btab  = (const float*)d_in[6];
    float* out = (float*)d_out;

    char* ws = (char*)d_ws;
    _Float16* wq_h = (_Float16*)(ws + WQH_OFF);
    _Float16* wp_h = (_Float16*)(ws + WPH_OFF);
    float*    rb   = (float*)(ws + RB_OFF);
    float*    rbm  = (float*)(ws + RBM_OFF);
    _Float16* xh   = (_Float16*)(ws + XH_OFF);

    const bool use_xh  = ws_size >= (size_t)WS_NEED_XH;
    const bool use_rbm = ws_size >= (size_t)WS_NEED_RBM;
    _Float16* ctx = (_Float16*)(ws + (use_rbm ? CTX_OFF : CTXL_OFF));

    hipLaunchKernelGGL(prep_kernel, dim3(use_rbm ? 7203 : 1728), dim3(256), 0, stream,
                       wqkv, wproj, btab, mask, wq_h, wp_h, rb, rbm, (int)use_rbm);
    if (use_xh) {
        hipLaunchKernelGGL(xcvt_kernel, dim3(2048), dim3(256), 0, stream, x, xh);
        hipLaunchKernelGGL((attn_kernel<true, true>), dim3(BNWIN), dim3(256), 0, stream,
                           x, xh, mask, wq_h, bqkv, rb, rbm, ctx);
    } else if (use_rbm) {
        hipLaunchKernelGGL((attn_kernel<false, true>), dim3(BNWIN), dim3(256), 0, stream,
                           x, xh, mask, wq_h, bqkv, rb, rbm, ctx);
    } else {
        hipLaunchKernelGGL((attn_kernel<false, false>), dim3(BNWIN), dim3(256), 0, stream,
                           x, xh, mask, wq_h, bqkv, rb, rbm, ctx);
    }
    hipLaunchKernelGGL(proj_kernel, dim3(MROWS / 64), dim3(256), 0, stream,
                       ctx, wp_h, bproj, out);
}

// Round 2
// 1542.980 us; speedup vs baseline: 1.2259x; 1.2259x over previous
//
#include <hip/hip_runtime.h>
#include <hip/hip_fp16.h>

#define NTOK   49
#define DIMM   384
#define NHEAD  12
#define HD     32
#define BNWIN  4096        // 64 windows * 64 batch

typedef _Float16 half8 __attribute__((ext_vector_type(8)));
typedef float    f32x4 __attribute__((ext_vector_type(4)));

// workspace layout (byte offsets, 256-aligned)
// wq_f: 442368 halves = 884736 B   (swizzled qkv weight, fragment order)
// wp_f: 147456 halves = 294912 B   (swizzled proj weight)
// rbm : 1843968 floats = 7375872 B (rel-bias + mask combined)
// xh_f: 77070336 halves = 154140672 B (swizzled fp16 x)
#define WQF_OFF   0u
#define WPF_OFF   884736u
#define RBM_OFF   1179648u
#define XHF_OFF   8555520u

// ---------------------------------------------------------------------------
// Kernel 0: weight swizzle to fragment order + combined bias+mask table
// wq_f[((T*12+k)*64+lane)*8+e] = wqkv[(T*16+(lane&15))*384 + k*32 + (lane>>4)*8 + e]
// so a wave's 64 lanes read one contiguous 1KB block per (tile,k).
// ---------------------------------------------------------------------------
__global__ __launch_bounds__(256) void prep_kernel(
    const float* __restrict__ wqkv, const float* __restrict__ wproj,
    const float* __restrict__ btab, const float* __restrict__ mask,
    _Float16* __restrict__ wqf, _Float16* __restrict__ wpf,
    float* __restrict__ rbm)
{
    int idx = blockIdx.x * 256 + threadIdx.x;
    if (idx < 55296) {            // 72 tiles * 12 k * 64 lanes
        int lane = idx & 63;
        int kk   = (idx >> 6) % 12;
        int T    = idx / 768;
        const float* s = wqkv + (size_t)(T * 16 + (lane & 15)) * DIMM + kk * 32 + (lane >> 4) * 8;
        _Float16* d = wqf + (size_t)idx * 8;
#pragma unroll
        for (int e = 0; e < 8; ++e) d[e] = (_Float16)s[e];
    }
    if (idx < 18432) {            // 24 tiles * 12 k * 64 lanes
        int lane = idx & 63;
        int kk   = (idx >> 6) % 12;
        int T    = idx / 768;
        const float* s = wproj + (size_t)(T * 16 + (lane & 15)) * DIMM + kk * 32 + (lane >> 4) * 8;
        _Float16* d = wpf + (size_t)idx * 8;
#pragma unroll
        for (int e = 0; e < 8; ++e) d[e] = (_Float16)s[e];
    }
    if (idx < 1843968) {
        // rbm[wm][h][i][j] = rb[h][i][j] + mask[wm][i][j]
        int wm  = idx / 28812;
        int rem = idx - wm * 28812;
        int h   = rem / 2401;
        int ij  = rem - h * 2401;
        int i   = ij / 49;
        int j   = ij - i * 49;
        int ih = i / 7, iw = i - ih * 7;
        int jh = j / 7, jw = j - jh * 7;
        int rel = (ih - jh + 6) * 13 + (iw - jw + 6);
        rbm[idx] = btab[rel * 12 + h] + mask[wm * 2401 + ij];
    }
}

// ---------------------------------------------------------------------------
// Kernel 0b: x fp32 -> fp16, swizzled to fragment order:
// xh_f[(((bn*12+k)*49+row)*4+quad)*8+e] = x[(bn*49+row)*384 + k*32 + quad*8 + e]
// A wave's (mi,k) fragment load becomes one contiguous 1KB block.
// ---------------------------------------------------------------------------
__global__ __launch_bounds__(256) void xswz_kernel(
    const float* __restrict__ x, _Float16* __restrict__ xh)
{
    const int total = BNWIN * 12 * NTOK * 4;   // 9,633,792 groups of 8
    int g = blockIdx.x * 256 + threadIdx.x;
    const int step = gridDim.x * 256;
    for (; g < total; g += step) {
        int quad = g & 3;
        int t    = g >> 2;
        int row  = t % 49;
        int t2   = t / 49;
        int k    = t2 % 12;
        int bn   = t2 / 12;
        const float* s = x + ((size_t)bn * NTOK + row) * DIMM + k * 32 + quad * 8;
        float4 a0 = *(const float4*)s;
        float4 a1 = *(const float4*)(s + 4);
        half8 v;
        v[0] = (_Float16)a0.x; v[1] = (_Float16)a0.y;
        v[2] = (_Float16)a0.z; v[3] = (_Float16)a0.w;
        v[4] = (_Float16)a1.x; v[5] = (_Float16)a1.y;
        v[6] = (_Float16)a1.z; v[7] = (_Float16)a1.w;
        *(half8*)(xh + (size_t)g * 8) = v;
    }
}

// ---------------------------------------------------------------------------
// Kernel 1: fully fused window attention + output projection.
// One block per window. 256 threads = 4 waves; wave w owns heads {w,w+4,w+8}.
// Per-head O held in fp16 registers; after all heads, dumped to a block-wide
// ctx LDS tile (aliasing the per-wave q/k/vT buffers), then out = ctx@Wp^T+bp.
// ---------------------------------------------------------------------------
__global__ __launch_bounds__(256, 3) void attn_kernel(
    const _Float16* __restrict__ xh,
    const _Float16* __restrict__ wq, const float* __restrict__ bq,
    const float* __restrict__ rbm,
    const _Float16* __restrict__ wp, const float* __restrict__ bp,
    float* __restrict__ out)
{
    // per-wave LDS (halves): [0,1960) q (49x40), [1960,3920) k (49x40)
    //                        [0,3528)  p (49x72)  -- aliases q/k after use
    //                        [3920,6224) vT (32 rows d x 72 cols j)
    // after final barrier the whole array aliases ctx_lds [49][400]
    __shared__ _Float16 smem[4][6224];
    const int tid  = threadIdx.x;
    const int wv   = tid >> 6;
    const int lane = tid & 63;
    const int quad = lane >> 4;
    const int l16  = lane & 15;
    const int bn   = blockIdx.x;
    const int wm   = bn >> 6;          // window index (B=64)

    _Float16* q_s  = &smem[wv][0];
    _Float16* k_s  = &smem[wv][1960];
    _Float16* p_s  = &smem[wv][0];
    _Float16* vT_s = &smem[wv][3920];
    _Float16* cl   = &smem[0][0];      // ctx_lds [49][400] after barrier

    const float scale = 0.17677669529663687f;  // 32^-0.5

    int rowm[4];
#pragma unroll
    for (int mi = 0; mi < 4; ++mi) {
        int r = mi * 16 + l16;
        rowm[mi] = r > 48 ? 48 : r;    // clamp: rows >=49 are finite clones of row 48
    }

    // A-fragment loader from swizzled xh_f: contiguous 1KB per (mi,k) wave-load
    auto load_af = [&](int k, half8* af) {
        const _Float16* base = xh + ((size_t)(bn * 12 + k) * NTOK) * 32 + quad * 8;
#pragma unroll
        for (int mi = 0; mi < 4; ++mi)
            af[mi] = *(const half8*)(base + rowm[mi] * 32);
    };
    // B-fragment loader from swizzled weights: one contiguous 1KB per (tile,k)
    auto load_bf = [&](const _Float16* w, int T, int k) -> half8 {
        return *(const half8*)(w + ((size_t)(T * 12 + k) * 64 + lane) * 8);
    };

    half8 oh[2][4];                    // fp16 O of heads 0,1 (held in regs)
    f32x4 o2[4][2];                    // fp32 O of head 2

    for (int hh = 0; hh < 3; ++hh) {
        const int h = wv + (hh << 2);

        // ---- V pass: v = x @ Wv^T (32 cols), K=384; scatter transposed ----
        {
            f32x4 av[2][4];
#pragma unroll
            for (int nv = 0; nv < 2; ++nv)
#pragma unroll
                for (int mi = 0; mi < 4; ++mi)
                    av[nv][mi] = (f32x4){0.f, 0.f, 0.f, 0.f};

#pragma unroll 4
            for (int k = 0; k < 12; ++k) {
                half8 af[4];
                load_af(k, af);
#pragma unroll
                for (int nv = 0; nv < 2; ++nv) {
                    const int T = 48 + h * 2 + nv;     // v tiles start at 48
                    half8 bf = load_bf(wq, T, k);
#pragma unroll
                    for (int mi = 0; mi < 4; ++mi)
                        av[nv][mi] = __builtin_amdgcn_mfma_f32_16x16x32_f16(af[mi], bf, av[nv][mi], 0, 0, 0);
                }
            }
#pragma unroll
            for (int nv = 0; nv < 2; ++nv) {
                const float bias = bq[(48 + h * 2 + nv) * 16 + l16];
                const int colh = nv * 16 + l16;
#pragma unroll
                for (int mi = 0; mi < 4; ++mi)
#pragma unroll
                    for (int r = 0; r < 4; ++r) {
                        const int row = mi * 16 + quad * 4 + r;
                        vT_s[colh * 72 + row] = (_Float16)(av[nv][mi][r] + bias);  // rows>=49: finite clones, P=0 there
                    }
            }
        }

        // ---- QK pass: q,k = x @ W^T (2x32 cols); q pre-scaled ----
        {
            f32x4 aqk[4][4];
#pragma unroll
            for (int nn = 0; nn < 4; ++nn)
#pragma unroll
                for (int mi = 0; mi < 4; ++mi)
                    aqk[nn][mi] = (f32x4){0.f, 0.f, 0.f, 0.f};

#pragma unroll 2
            for (int k = 0; k < 12; ++k) {
                half8 af[4];
                load_af(k, af);
#pragma unroll
                for (int nn = 0; nn < 4; ++nn) {
                    const int T = (nn < 2) ? (h * 2 + nn) : (24 + h * 2 + (nn - 2));
                    half8 bf = load_bf(wq, T, k);
#pragma unroll
                    for (int mi = 0; mi < 4; ++mi)
                        aqk[nn][mi] = __builtin_amdgcn_mfma_f32_16x16x32_f16(af[mi], bf, aqk[nn][mi], 0, 0, 0);
                }
            }
#pragma unroll
            for (int nn = 0; nn < 4; ++nn) {
                const int T = (nn < 2) ? (h * 2 + nn) : (24 + h * 2 + (nn - 2));
                const float bias = bq[T * 16 + l16];
                const int colh = (nn & 1) * 16 + l16;
                if (nn < 2) {
                    const float bs = bias * scale;
#pragma unroll
                    for (int mi = 0; mi < 4; ++mi)
#pragma unroll
                        for (int r = 0; r < 4; ++r) {
                            const int row = mi * 16 + quad * 4 + r;
                            if (row < 49) q_s[row * 40 + colh] = (_Float16)(aqk[nn][mi][r] * scale + bs);
                        }
                } else {
#pragma unroll
                    for (int mi = 0; mi < 4; ++mi)
#pragma unroll
                        for (int r = 0; r < 4; ++r) {
                            const int row = mi * 16 + quad * 4 + r;
                            if (row < 49) k_s[row * 40 + colh] = (_Float16)(aqk[nn][mi][r] + bias);
                        }
                }
            }
        }

        // ---- phase 2: S = q @ k^T (q pre-scaled), K=32 single MFMA step ----
        f32x4 s[4][4];
        {
            half8 bk[4];
#pragma unroll
            for (int nj = 0; nj < 4; ++nj)
                bk[nj] = *(const half8*)(k_s + rowm[nj] * 40 + quad * 8);
#pragma unroll
            for (int mi = 0; mi < 4; ++mi) {
                half8 aq = *(const half8*)(q_s + rowm[mi] * 40 + quad * 8);
#pragma unroll
                for (int nj = 0; nj < 4; ++nj)
                    s[mi][nj] = __builtin_amdgcn_mfma_f32_16x16x32_f16(
                        aq, bk[nj], (f32x4){0.f, 0.f, 0.f, 0.f}, 0, 0, 0);
            }
        }

        // ---- phase 3: +(bias+mask), register softmax, P -> LDS ----
        const float* rbmh = rbm + (size_t)(wm * 12 + h) * 2401;
#pragma unroll
        for (int mi = 0; mi < 4; ++mi) {
#pragma unroll
            for (int r = 0; r < 4; ++r) {
                const int i  = mi * 16 + quad * 4 + r;
                const int iq = i > 48 ? 48 : i;
                float vals[4];
                float mx = -3.0e38f;
#pragma unroll
                for (int nj = 0; nj < 4; ++nj) {
                    const int j = nj * 16 + l16;
                    float v = -1.0e30f;
                    if (j < 49)
                        v = s[mi][nj][r] + rbmh[iq * 49 + j];
                    vals[nj] = v;
                    mx = fmaxf(mx, v);
                }
#pragma unroll
                for (int off = 8; off >= 1; off >>= 1)
                    mx = fmaxf(mx, __shfl_xor(mx, off));
                float sum = 0.f;
#pragma unroll
                for (int nj = 0; nj < 4; ++nj) {
                    vals[nj] = __expf(vals[nj] - mx);
                    sum += vals[nj];
                }
#pragma unroll
                for (int off = 8; off >= 1; off >>= 1)
                    sum += __shfl_xor(sum, off);
                const float inv = __builtin_amdgcn_rcpf(sum);
                if (i < 49) {
#pragma unroll
                    for (int nj = 0; nj < 4; ++nj)
                        p_s[i * 72 + nj * 16 + l16] = (_Float16)(vals[nj] * inv);
                }
            }
        }

        // ---- phase 4: O = P @ V ----
        f32x4 o[4][2];
#pragma unroll
        for (int mi = 0; mi < 4; ++mi)
#pragma unroll
            for (int nd = 0; nd < 2; ++nd)
                o[mi][nd] = (f32x4){0.f, 0.f, 0.f, 0.f};
#pragma unroll
        for (int ks = 0; ks < 2; ++ks) {
            half8 bv[2];
#pragma unroll
            for (int nd = 0; nd < 2; ++nd)
                bv[nd] = *(const half8*)(vT_s + (nd * 16 + l16) * 72 + ks * 32 + quad * 8);
#pragma unroll
            for (int mi = 0; mi < 4; ++mi) {
                half8 apf = *(const half8*)(p_s + rowm[mi] * 72 + ks * 32 + quad * 8);
#pragma unroll
                for (int nd = 0; nd < 2; ++nd)
                    o[mi][nd] = __builtin_amdgcn_mfma_f32_16x16x32_f16(apf, bv[nd], o[mi][nd], 0, 0, 0);
            }
        }

        // ---- hold O: heads 0,1 packed fp16 in regs; head 2 stays fp32 ----
        if (hh < 2) {
#pragma unroll
            for (int mi = 0; mi < 4; ++mi) {
                half8 t;
#pragma unroll
                for (int nd = 0; nd < 2; ++nd)
#pragma unroll
                    for (int r = 0; r < 4; ++r)
                        t[nd * 4 + r] = (_Float16)o[mi][nd][r];
                oh[hh][mi] = t;
            }
        } else {
#pragma unroll
            for (int mi = 0; mi < 4; ++mi)
#pragma unroll
                for (int nd = 0; nd < 2; ++nd)
                    o2[mi][nd] = o[mi][nd];
        }
    }

    // ---- dump all heads' O into block-wide ctx LDS tile [49][400] ----
    __syncthreads();   // everyone done with per-wave smem
#pragma unroll
    for (int hh = 0; hh < 2; ++hh) {
        const int h = wv + (hh << 2);
#pragma unroll
        for (int mi = 0; mi < 4; ++mi)
#pragma unroll
            for (int nd = 0; nd < 2; ++nd)
#pragma unroll
                for (int r = 0; r < 4; ++r) {
                    const int row = mi * 16 + quad * 4 + r;
                    if (row < 49)
                        cl[row * 400 + h * HD + nd * 16 + l16] = oh[hh][mi][nd * 4 + r];
                }
    }
    {
        const int h = wv + 8;
#pragma unroll
        for (int mi = 0; mi < 4; ++mi)
#pragma unroll
            for (int nd = 0; nd < 2; ++nd)
#pragma unroll
                for (int r = 0; r < 4; ++r) {
                    const int row = mi * 16 + quad * 4 + r;
                    if (row < 49)
                        cl[row * 400 + h * HD + nd * 16 + l16] = (_Float16)o2[mi][nd][r];
                }
    }
    __syncthreads();

    // ---- fused projection: out = ctx @ Wp^T + bp; wave wv covers 96 cols ----
    {
        f32x4 c[6][4];
#pragma unroll
        for (int nj = 0; nj < 6; ++nj)
#pragma unroll
            for (int mi = 0; mi < 4; ++mi)
                c[nj][mi] = (f32x4){0.f, 0.f, 0.f, 0.f};

#pragma unroll 2
        for (int k = 0; k < 12; ++k) {
            half8 a[4];
#pragma unroll
            for (int mi = 0; mi < 4; ++mi)
                a[mi] = *(const half8*)(cl + rowm[mi] * 400 + k * 32 + quad * 8);
#pragma unroll
            for (int nj = 0; nj < 6; ++nj) {
                half8 b = load_bf(wp, wv * 6 + nj, k);
#pragma unroll
                for (int mi = 0; mi < 4; ++mi)
                    c[nj][mi] = __builtin_amdgcn_mfma_f32_16x16x32_f16(a[mi], b, c[nj][mi], 0, 0, 0);
            }
        }
#pragma unroll
        for (int nj = 0; nj < 6; ++nj) {
            const int n = (wv * 6 + nj) * 16 + l16;
            const float bias = bp[n];
#pragma unroll
            for (int mi = 0; mi < 4; ++mi) {
#pragma unroll
                for (int r = 0; r < 4; ++r) {
                    const int i = mi * 16 + quad * 4 + r;
                    if (i < 49)
                        out[((size_t)bn * NTOK + i) * DIMM + n] = c[nj][mi][r] + bias;
                }
            }
        }
    }
}

// ---------------------------------------------------------------------------
extern "C" void kernel_launch(void* const* d_in, const int* in_sizes, int n_in,
                              void* d_out, int out_size, void* d_ws, size_t ws_size,
                              hipStream_t stream)
{
    const float* x     = (const float*)d_in[0];
    const float* mask  = (const float*)d_in[1];
    const float* wqkv  = (const float*)d_in[2];
    const float* bqkv  = (const float*)d_in[3];
    const float* wproj = (const float*)d_in[4];
    const float* bproj = (const float*)d_in[5];
    const float* btab  = (const float*)d_in[6];
    float* out = (float*)d_out;

    char* ws = (char*)d_ws;
    _Float16* wq_f = (_Float16*)(ws + WQF_OFF);
    _Float16* wp_f = (_Float16*)(ws + WPF_OFF);
    float*    rbm  = (float*)(ws + RBM_OFF);
    _Float16* xh_f = (_Float16*)(ws + XHF_OFF);

    hipLaunchKernelGGL(prep_kernel, dim3(7203), dim3(256), 0, stream,
                       wqkv, wproj, btab, mask, wq_f, wp_f, rbm);
    hipLaunchKernelGGL(xswz_kernel, dim3(2048), dim3(256), 0, stream, x, xh_f);
    hipLaunchKernelGGL(attn_kernel, dim3(BNWIN), dim3(256), 0, stream,
                       xh_f, wq_f, bqkv, rbm, wp_f, bproj, out);
}

// Round 3
// 1439.588 us; speedup vs baseline: 1.3139x; 1.0718x over previous
//
#include <hip/hip_runtime.h>
#include <hip/hip_fp16.h>

#define NTOK   49
#define DIMM   384
#define NHEAD  12
#define HD     32
#define BNWIN  4096        // 64 windows * 64 batch

typedef _Float16 half8 __attribute__((ext_vector_type(8)));
typedef _Float16 half4 __attribute__((ext_vector_type(4)));
typedef float    f32x4 __attribute__((ext_vector_type(4)));

// workspace layout (byte offsets, 256-aligned)
// wq_f : 442368 halves =   884736 B (swizzled qkv weight, fragment order)
// wp_f : 147456 halves =   294912 B (swizzled proj weight)
// rbm_f: 3145728 halves =  6291456 B (rel-bias+mask, fp16 fragment layout, padded 64x64)
// xh_f : 77070336 halves = 154140672 B (swizzled fp16 x)
#define WQF_OFF   0u
#define WPF_OFF   884736u
#define RBMF_OFF  1179648u
#define XHF_OFF   7471104u

// ---------------------------------------------------------------------------
// Kernel 0: weight swizzle to fragment order + fp16 fragment bias+mask table
// wq_f[((T*12+k)*64+lane)*8+e] = wqkv[(T*16+(lane&15))*384 + k*32 + (lane>>4)*8 + e]
// rbm_f[wm][h][((mi*4+nj)*64+lane)*4+r] = bias+mask at (i=mi*16+(lane>>4)*4+r,
//   j=nj*16+(lane&15)); i>=49 -> row-48 clone; j>=49 -> -30000 (exp -> 0)
// ---------------------------------------------------------------------------
__global__ __launch_bounds__(256) void prep_kernel(
    const float* __restrict__ wqkv, const float* __restrict__ wproj,
    const float* __restrict__ btab, const float* __restrict__ mask,
    _Float16* __restrict__ wqf, _Float16* __restrict__ wpf,
    _Float16* __restrict__ rbmf)
{
    int idx = blockIdx.x * 256 + threadIdx.x;
    if (idx < 55296) {            // 72 tiles * 12 k * 64 lanes
        int lane = idx & 63;
        int kk   = (idx >> 6) % 12;
        int T    = idx / 768;
        const float* s = wqkv + (size_t)(T * 16 + (lane & 15)) * DIMM + kk * 32 + (lane >> 4) * 8;
        _Float16* d = wqf + (size_t)idx * 8;
#pragma unroll
        for (int e = 0; e < 8; ++e) d[e] = (_Float16)s[e];
    }
    if (idx < 18432) {            // 24 tiles * 12 k * 64 lanes
        int lane = idx & 63;
        int kk   = (idx >> 6) % 12;
        int T    = idx / 768;
        const float* s = wproj + (size_t)(T * 16 + (lane & 15)) * DIMM + kk * 32 + (lane >> 4) * 8;
        _Float16* d = wpf + (size_t)idx * 8;
#pragma unroll
        for (int e = 0; e < 8; ++e) d[e] = (_Float16)s[e];
    }
    if (idx < 3145728) {          // 64 wm * 12 h * 4096 entries
        int wm  = idx >> 15;                 // /(12*4096) ... 12*4096=49152; use div
        wm = idx / 49152;
        int rem = idx - wm * 49152;
        int h   = rem / 4096;
        int e   = rem - h * 4096;
        int r    = e & 3;
        int lane = (e >> 2) & 63;
        int t    = e >> 8;
        int nj   = t & 3;
        int mi   = t >> 2;
        int i = mi * 16 + (lane >> 4) * 4 + r;
        int j = nj * 16 + (lane & 15);
        float val = -30000.f;
        if (j < 49) {
            int ii = i > 48 ? 48 : i;
            int ih = ii / 7, iw = ii - ih * 7;
            int jh = j / 7,  jw = j - jh * 7;
            int rel = (ih - jh + 6) * 13 + (iw - jw + 6);
            val = btab[rel * 12 + h] + mask[wm * 2401 + ii * 49 + j];
        }
        rbmf[idx] = (_Float16)val;
    }
}

// ---------------------------------------------------------------------------
// Kernel 0b: x fp32 -> fp16, swizzled to fragment order:
// xh_f[(((bn*12+k)*49+row)*4+quad)*8+e] = x[(bn*49+row)*384 + k*32 + quad*8 + e]
// ---------------------------------------------------------------------------
__global__ __launch_bounds__(256) void xswz_kernel(
    const float* __restrict__ x, _Float16* __restrict__ xh)
{
    const int total = BNWIN * 12 * NTOK * 4;   // 9,633,792 groups of 8
    int g = blockIdx.x * 256 + threadIdx.x;
    const int step = gridDim.x * 256;
    for (; g < total; g += step) {
        int quad = g & 3;
        int t    = g >> 2;
        int row  = t % 49;
        int t2   = t / 49;
        int k    = t2 % 12;
        int bn   = t2 / 12;
        const float* s = x + ((size_t)bn * NTOK + row) * DIMM + k * 32 + quad * 8;
        float4 a0 = *(const float4*)s;
        float4 a1 = *(const float4*)(s + 4);
        half8 v;
        v[0] = (_Float16)a0.x; v[1] = (_Float16)a0.y;
        v[2] = (_Float16)a0.z; v[3] = (_Float16)a0.w;
        v[4] = (_Float16)a1.x; v[5] = (_Float16)a1.y;
        v[6] = (_Float16)a1.z; v[7] = (_Float16)a1.w;
        *(half8*)(xh + (size_t)g * 8) = v;
    }
}

// ---------------------------------------------------------------------------
// Kernel 1: fully fused window attention + output projection.
// One block per window (XCD-chunk-swizzled). 4 waves; wave w owns heads
// {w,w+4,w+8}. Single merged QKV pass (6 acc tiles). O held in fp16 regs.
// Projection result re-tiled through LDS for full-row float4 stores.
// ---------------------------------------------------------------------------
__global__ __launch_bounds__(256, 3) void attn_kernel(
    const _Float16* __restrict__ xh,
    const _Float16* __restrict__ wq, const float* __restrict__ bq,
    const _Float16* __restrict__ rbmf,
    const _Float16* __restrict__ wp, const float* __restrict__ bp,
    float* __restrict__ out)
{
    // per-wave LDS (halves): [0,1960) q (49x40), [1960,3920) k (49x40)
    //                        [0,3528)  p (49x72)  -- aliases q/k after use
    //                        [3920,6224) vT (32 rows d x 72 cols j)
    // block-wide after barriers: cl = ctx [49][404] fp16; fls = [49][196] fp32
    __shared__ _Float16 smem[4][6224];
    const int tid  = threadIdx.x;
    const int wv   = tid >> 6;
    const int lane = tid & 63;
    const int quad = lane >> 4;
    const int l16  = lane & 15;
    const int bn   = ((blockIdx.x & 7) << 9) | (blockIdx.x >> 3);  // XCD chunk swizzle
    const int wm   = bn >> 6;          // window index (B=64)

    _Float16* q_s  = &smem[wv][0];
    _Float16* k_s  = &smem[wv][1960];
    _Float16* p_s  = &smem[wv][0];
    _Float16* vT_s = &smem[wv][3920];
    _Float16* cl   = &smem[0][0];      // ctx_lds [49][404] after barrier
    float*    fls  = (float*)&smem[0][0];  // [49][196] fp32 epilogue tile

    const float scale = 0.17677669529663687f;  // 32^-0.5

    int rowm[4];
#pragma unroll
    for (int mi = 0; mi < 4; ++mi) {
        int r = mi * 16 + l16;
        rowm[mi] = r > 48 ? 48 : r;    // clamp: rows >=49 are finite clones of row 48
    }

    // A-fragment loader from swizzled xh_f: contiguous 1KB per (mi,k) wave-load
    auto load_af = [&](int k, half8* af) {
        const _Float16* base = xh + ((size_t)(bn * 12 + k) * NTOK) * 32 + quad * 8;
#pragma unroll
        for (int mi = 0; mi < 4; ++mi)
            af[mi] = *(const half8*)(base + rowm[mi] * 32);
    };
    // B-fragment loader from swizzled weights: one contiguous 1KB per (tile,k)
    auto load_bf = [&](const _Float16* w, int T, int k) -> half8 {
        return *(const half8*)(w + ((size_t)(T * 12 + k) * 64 + lane) * 8);
    };

    half8 oh[2][4];                    // fp16 O of heads 0,1 (held in regs)
    f32x4 o2[4][2];                    // fp32 O of head 2

    for (int hh = 0; hh < 3; ++hh) {
        const int h = wv + (hh << 2);
        // tile ids: q: h*2, h*2+1 | k: 24+h*2, 25+h*2 | v: 48+h*2, 49+h*2
        int tT[6];
        tT[0] = h * 2;      tT[1] = h * 2 + 1;
        tT[2] = 24 + h * 2; tT[3] = 25 + h * 2;
        tT[4] = 48 + h * 2; tT[5] = 49 + h * 2;

        // ---- merged QKV pass: 6 output tiles (q0 q1 k0 k1 v0 v1), K=384 ----
        f32x4 acc[6][4];
#pragma unroll
        for (int t = 0; t < 6; ++t)
#pragma unroll
            for (int mi = 0; mi < 4; ++mi)
                acc[t][mi] = (f32x4){0.f, 0.f, 0.f, 0.f};

#pragma unroll 2
        for (int k = 0; k < 12; ++k) {
            half8 af[4];
            load_af(k, af);
#pragma unroll
            for (int t = 0; t < 6; ++t) {
                half8 bf = load_bf(wq, tT[t], k);
#pragma unroll
                for (int mi = 0; mi < 4; ++mi)
                    acc[t][mi] = __builtin_amdgcn_mfma_f32_16x16x32_f16(af[mi], bf, acc[t][mi], 0, 0, 0);
            }
        }

        // scatter: q (pre-scaled) / k row-major, v transposed
#pragma unroll
        for (int t = 0; t < 6; ++t) {
            const float bias = bq[tT[t] * 16 + l16];
            const int colh = (t & 1) * 16 + l16;
            if (t < 2) {
                const float bs = bias * scale;
#pragma unroll
                for (int mi = 0; mi < 4; ++mi)
#pragma unroll
                    for (int r = 0; r < 4; ++r) {
                        const int row = mi * 16 + quad * 4 + r;
                        if (row < 49) q_s[row * 40 + colh] = (_Float16)(acc[t][mi][r] * scale + bs);
                    }
            } else if (t < 4) {
#pragma unroll
                for (int mi = 0; mi < 4; ++mi)
#pragma unroll
                    for (int r = 0; r < 4; ++r) {
                        const int row = mi * 16 + quad * 4 + r;
                        if (row < 49) k_s[row * 40 + colh] = (_Float16)(acc[t][mi][r] + bias);
                    }
            } else {
#pragma unroll
                for (int mi = 0; mi < 4; ++mi)
#pragma unroll
                    for (int r = 0; r < 4; ++r) {
                        const int row = mi * 16 + quad * 4 + r;
                        vT_s[colh * 72 + row] = (_Float16)(acc[t][mi][r] + bias);  // rows>=49: clones, P=0 there
                    }
            }
        }

        // ---- phase 2: S = q @ k^T (q pre-scaled), K=32 single MFMA step ----
        f32x4 s[4][4];
        {
            half8 bk[4];
#pragma unroll
            for (int nj = 0; nj < 4; ++nj)
                bk[nj] = *(const half8*)(k_s + rowm[nj] * 40 + quad * 8);
#pragma unroll
            for (int mi = 0; mi < 4; ++mi) {
                half8 aq = *(const half8*)(q_s + rowm[mi] * 40 + quad * 8);
#pragma unroll
                for (int nj = 0; nj < 4; ++nj)
                    s[mi][nj] = __builtin_amdgcn_mfma_f32_16x16x32_f16(
                        aq, bk[nj], (f32x4){0.f, 0.f, 0.f, 0.f}, 0, 0, 0);
            }
        }

        // ---- phase 3: +(bias+mask) fp16 fragment table, register softmax ----
        const _Float16* rbmh = rbmf + (size_t)(wm * 12 + h) * 4096;
#pragma unroll
        for (int mi = 0; mi < 4; ++mi) {
            half4 rv[4];
#pragma unroll
            for (int nj = 0; nj < 4; ++nj)
                rv[nj] = *(const half4*)(rbmh + ((mi * 4 + nj) * 64 + lane) * 4);
#pragma unroll
            for (int r = 0; r < 4; ++r) {
                const int i = mi * 16 + quad * 4 + r;
                float vals[4];
                float mx = -3.0e38f;
#pragma unroll
                for (int nj = 0; nj < 4; ++nj) {
                    float v = s[mi][nj][r] + (float)rv[nj][r];
                    vals[nj] = v;
                    mx = fmaxf(mx, v);
                }
#pragma unroll
                for (int off = 8; off >= 1; off >>= 1)
                    mx = fmaxf(mx, __shfl_xor(mx, off));
                float sum = 0.f;
#pragma unroll
                for (int nj = 0; nj < 4; ++nj) {
                    vals[nj] = __expf(vals[nj] - mx);
                    sum += vals[nj];
                }
#pragma unroll
                for (int off = 8; off >= 1; off >>= 1)
                    sum += __shfl_xor(sum, off);
                const float inv = __builtin_amdgcn_rcpf(sum);
                if (i < 49) {
#pragma unroll
                    for (int nj = 0; nj < 4; ++nj)
                        p_s[i * 72 + nj * 16 + l16] = (_Float16)(vals[nj] * inv);
                }
            }
        }

        // ---- phase 4: O = P @ V ----
        f32x4 o[4][2];
#pragma unroll
        for (int mi = 0; mi < 4; ++mi)
#pragma unroll
            for (int nd = 0; nd < 2; ++nd)
                o[mi][nd] = (f32x4){0.f, 0.f, 0.f, 0.f};
#pragma unroll
        for (int ks = 0; ks < 2; ++ks) {
            half8 bv[2];
#pragma unroll
            for (int nd = 0; nd < 2; ++nd)
                bv[nd] = *(const half8*)(vT_s + (nd * 16 + l16) * 72 + ks * 32 + quad * 8);
#pragma unroll
            for (int mi = 0; mi < 4; ++mi) {
                half8 apf = *(const half8*)(p_s + rowm[mi] * 72 + ks * 32 + quad * 8);
#pragma unroll
                for (int nd = 0; nd < 2; ++nd)
                    o[mi][nd] = __builtin_amdgcn_mfma_f32_16x16x32_f16(apf, bv[nd], o[mi][nd], 0, 0, 0);
            }
        }

        // ---- hold O: heads 0,1 packed fp16 in regs; head 2 stays fp32 ----
        if (hh < 2) {
#pragma unroll
            for (int mi = 0; mi < 4; ++mi) {
                half8 t;
#pragma unroll
                for (int nd = 0; nd < 2; ++nd)
#pragma unroll
                    for (int r = 0; r < 4; ++r)
                        t[nd * 4 + r] = (_Float16)o[mi][nd][r];
                oh[hh][mi] = t;
            }
        } else {
#pragma unroll
            for (int mi = 0; mi < 4; ++mi)
#pragma unroll
                for (int nd = 0; nd < 2; ++nd)
                    o2[mi][nd] = o[mi][nd];
        }
    }

    // ---- dump all heads' O into block-wide ctx LDS tile [49][404] ----
    __syncthreads();   // everyone done with per-wave smem
#pragma unroll
    for (int hh = 0; hh < 2; ++hh) {
        const int h = wv + (hh << 2);
#pragma unroll
        for (int mi = 0; mi < 4; ++mi)
#pragma unroll
            for (int nd = 0; nd < 2; ++nd)
#pragma unroll
                for (int r = 0; r < 4; ++r) {
                    const int row = mi * 16 + quad * 4 + r;
                    if (row < 49)
                        cl[row * 404 + h * HD + nd * 16 + l16] = oh[hh][mi][nd * 4 + r];
                }
    }
    {
        const int h = wv + 8;
#pragma unroll
        for (int mi = 0; mi < 4; ++mi)
#pragma unroll
            for (int nd = 0; nd < 2; ++nd)
#pragma unroll
                for (int r = 0; r < 4; ++r) {
                    const int row = mi * 16 + quad * 4 + r;
                    if (row < 49)
                        cl[row * 404 + h * HD + nd * 16 + l16] = (_Float16)o2[mi][nd][r];
                }
    }
    __syncthreads();

    // ---- fused projection: ctx @ Wp^T + bp; wave wv covers cols [wv*96,+96) ----
    f32x4 c[6][4];
#pragma unroll
    for (int nj = 0; nj < 6; ++nj)
#pragma unroll
        for (int mi = 0; mi < 4; ++mi)
            c[nj][mi] = (f32x4){0.f, 0.f, 0.f, 0.f};

#pragma unroll 2
    for (int k = 0; k < 12; ++k) {
        half8 a[4];
#pragma unroll
        for (int mi = 0; mi < 4; ++mi)
            a[mi] = *(const half8*)(cl + rowm[mi] * 404 + k * 32 + quad * 8);
#pragma unroll
        for (int nj = 0; nj < 6; ++nj) {
            half8 b = load_bf(wp, wv * 6 + nj, k);
#pragma unroll
            for (int mi = 0; mi < 4; ++mi)
                c[nj][mi] = __builtin_amdgcn_mfma_f32_16x16x32_f16(a[mi], b, c[nj][mi], 0, 0, 0);
        }
    }

    // bias for this wave's 6 col-tiles
    float bias6[6];
#pragma unroll
    for (int nj = 0; nj < 6; ++nj)
        bias6[nj] = bp[wv * 96 + nj * 16 + l16];

    // ---- epilogue: re-tile through LDS, emit full-row float4 stores ----
    // pass p covers global cols [p*192, p*192+192); waves 2p, 2p+1 stage.
#pragma unroll 1
    for (int pass = 0; pass < 2; ++pass) {
        __syncthreads();   // pass0: proj reads of cl done; pass1: prior copy done
        if ((wv >> 1) == pass) {
            const int cbase = (wv & 1) * 96;
#pragma unroll
            for (int nj = 0; nj < 6; ++nj)
#pragma unroll
                for (int mi = 0; mi < 4; ++mi)
#pragma unroll
                    for (int r = 0; r < 4; ++r) {
                        const int row = mi * 16 + quad * 4 + r;
                        if (row < 49)
                            fls[row * 196 + cbase + nj * 16 + l16] = c[nj][mi][r] + bias6[nj];
                    }
        }
        __syncthreads();
        // block-wide copy: 49 rows x 192 cols = 2352 float4
        for (int g = tid; g < 2352; g += 256) {
            const int row = g / 48;
            const int c4  = g - row * 48;
            float4 v = *(const float4*)(fls + row * 196 + c4 * 4);
            *(float4*)(out + ((size_t)bn * NTOK + row) * DIMM + pass * 192 + c4 * 4) = v;
        }
    }
}

// ---------------------------------------------------------------------------
extern "C" void kernel_launch(void* const* d_in, const int* in_sizes, int n_in,
                              void* d_out, int out_size, void* d_ws, size_t ws_size,
                              hipStream_t stream)
{
    const float* x     = (const float*)d_in[0];
    const float* mask  = (const float*)d_in[1];
    const float* wqkv  = (const float*)d_in[2];
    const float* bqkv  = (const float*)d_in[3];
    const float* wproj = (const float*)d_in[4];
    const float* bproj = (const float*)d_in[5];
    const float* btab  = (const float*)d_in[6];
    float* out = (float*)d_out;

    char* ws = (char*)d_ws;
    _Float16* wq_f  = (_Float16*)(ws + WQF_OFF);
    _Float16* wp_f  = (_Float16*)(ws + WPF_OFF);
    _Float16* rbm_f = (_Float16*)(ws + RBMF_OFF);
    _Float16* xh_f  = (_Float16*)(ws + XHF_OFF);

    hipLaunchKernelGGL(prep_kernel, dim3(12288), dim3(256), 0, stream,
                       wqkv, wproj, btab, mask, wq_f, wp_f, rbm_f);
    hipLaunchKernelGGL(xswz_kernel, dim3(2048), dim3(256), 0, stream, x, xh_f);
    hipLaunchKernelGGL(attn_kernel, dim3(BNWIN), dim3(256), 0, stream,
                       xh_f, wq_f, bqkv, rbm_f, wp_f, bproj, out);
}